// Round 5
// baseline (148.540 us; speedup 1.0000x reference)
//
#include <hip/hip_runtime.h>
#include <math.h>

// Problem constants (match reference)
constexpr int cB = 2, cN = 8192, cS = 4096;
constexpr int cTR = 12;    // stored trans channels (0-5 before, 6-11 after)
constexpr int CAP = 96;    // survivor slots per query per half
constexpr int QPB = 8;     // queries per knn block (octet); block also owns a candidate HALF

typedef unsigned long long ull;

// ---- exact distance: EXACTLY mirrors reference arithmetic ----
// ref: sq = (x*x + y*y) + z*z ; d2 = (sq_i + sq_j) - 2*dot ; d = sqrt(max(d2,1e-12))
__device__ __forceinline__ float d2exact_rn(float qx, float qy, float qz, float qw,
                                            float cx, float cy, float cz, float cw) {
  float dot = __fadd_rn(__fadd_rn(__fmul_rn(qx, cx), __fmul_rn(qy, cy)), __fmul_rn(qz, cz));
  return __fsub_rn(__fadd_rn(qw, cw), __fmul_rn(2.0f, dot));
}
__device__ __forceinline__ float dist_rn4(float4 a, float4 b) {
  return sqrtf(fmaxf(d2exact_rn(a.x, a.y, a.z, a.w, b.x, b.y, b.z, b.w), 1e-12f));
}
__device__ __forceinline__ void ce64(ull& a, ull& b) {
  ull lo = a < b ? a : b;
  ull hi = a < b ? b : a;
  a = lo; b = hi;
}
__device__ __forceinline__ void cef(float& a, float& b) {
  float lo = fminf(a, b), hi = fmaxf(a, b);
  a = lo; b = hi;
}
// 6-step bitonic top-4 butterfly over 64 lanes. Input: per-lane SORTED quad a0<=a1<=a2<=a3.
// Output: all lanes hold the sorted 4 smallest of all 256 values. (Verified r2.)
__device__ __forceinline__ void top4_merge64(float& a0, float& a1, float& a2, float& a3) {
  #pragma unroll
  for (int off = 1; off < 64; off <<= 1) {
    float s0 = __shfl_xor(a0, off, 64), s1 = __shfl_xor(a1, off, 64);
    float s2 = __shfl_xor(a2, off, 64), s3 = __shfl_xor(a3, off, 64);
    float n0 = fminf(a0, s3), n1 = fminf(a1, s2), n2 = fminf(a2, s1), n3 = fminf(a3, s0);
    float t;
    t = fminf(n0, n2); n2 = fmaxf(n0, n2); n0 = t;
    t = fminf(n1, n3); n3 = fmaxf(n1, n3); n1 = t;
    t = fminf(n0, n1); n1 = fmaxf(n0, n1); n0 = t;
    t = fminf(n2, n3); n3 = fmaxf(n2, n3); n2 = t;
    a0 = n0; a1 = n1; a2 = n2; a3 = n3;
  }
}

// ---- K1: pack. P = orig order (clean sq); P2 = sampled-first permuted; idxMap -> orig ----
__global__ __launch_bounds__(512) void pack_kernel(const float* __restrict__ xyz,
                                                   const int* __restrict__ smp,
                                                   float4* __restrict__ P,
                                                   float4* __restrict__ P2,
                                                   int* __restrict__ idxMap,
                                                   float* __restrict__ oxyz) {
  int t = blockIdx.x * 512 + threadIdx.x;
  if (t < cB * cN) {
    int b = t >> 13, n = t & (cN - 1);
    const float* p = xyz + t * 3;
    float x = p[0], y = p[1], z = p[2];
    float sq = __fadd_rn(__fadd_rn(__fmul_rn(x, x), __fmul_rn(y, y)), __fmul_rn(z, z));
    const int* sb = smp + b * cS;
    int lo = 0, hi = cS;
    while (lo < hi) { int mid = (lo + hi) >> 1; if (sb[mid] < n) lo = mid + 1; else hi = mid; }
    bool flg = (lo < cS) && (sb[lo] == n);
    P[t] = make_float4(x, y, z, sq);
    int pos = flg ? lo : (cS + n - lo);
    int gp = b * cN + pos;
    P2[gp] = make_float4(x, y, z, sq);
    idxMap[gp] = n;
  } else if (t < cB * cN + cB * cS) {
    int j = t - cB * cN;
    int b = j >> 12;
    const float* p = xyz + (b * cN + smp[j]) * 3;
    oxyz[j * 3 + 0] = p[0]; oxyz[j * 3 + 1] = p[1]; oxyz[j * 3 + 2] = p[2];
  }
}

// ---- K2: 4-NN, split-half octet scan. r5 design:
// 2048 blocks (8 waves/SIMD preserved — r3's QPB=8 regression was the 1024-block occupancy
// collapse, not register pressure). block = (query octet qoct, half). Half h:
//   Pass A over sampled[h*2048, h*2048+2048) -> per-lane fast minima (f' = cp.w - 2*dot,
//     q.w folded out, HW-verified r1). Gate over a SUBSET of sampled is still a valid
//     upper bound: g >= 4th(sampled-subset) >= 4th(sampled) >= 4th(global), so any
//     candidate failing the gate has >=4 closer candidates — not in any top-4.
//   tau via LDS-transpose reduction (r2-verified), wave wv reduces queries 2wv,2wv+1.
//   Pass B over full[h*4096, (h+1)*4096) -> survivors (positions) per query.
//   Final: exact reference-rounded d2 keys + u64 butterfly -> EXACT within-half top-4,
//     written as raw u64 keys to PT. Half-0's Pass-B region == sampled region, so mode-1
//     comes entirely from half-0. Half-0 mode-0 survivors >= 4 always (the 4 nearest of
//     its gate subset pass the gate), so merged mode-0 keys are never sentinels.
// Per-thread candidate visits: 48 -> 24 (loads/addressing/loop halved; pair-fma invariant).
// NO per-thread candidate cache (r1 lesson: scratch spill). All per-query state NAMED
// scalars via macros (registers).
#define KNN_FORQ(M) M(0) M(1) M(2) M(3) M(4) M(5) M(6) M(7)

__global__ __launch_bounds__(256, 4) void knn_kernel(const float4* __restrict__ P2,
                                                     const int* __restrict__ idxMap,
                                                     ull* __restrict__ PT) {
  __shared__ int sPos[QPB][CAP];
  __shared__ int sCnt[QPB];
  __shared__ alignas(16) float tmpAll[QPB][256];   // [query][tid] lane minima
  __shared__ alignas(16) float gBuf[QPB];

  const int tid = threadIdx.x, wv = tid >> 6, lane = tid & 63;
  const int blk = blockIdx.x;
  const int half = blk & 1;
  const int qbase = (blk >> 1) * QPB;      // 8 | 4096 -> same batch
  const int b = qbase >> 12;
  const int s0 = qbase & (cS - 1);
  const float4* Cb = P2 + b * cN;
  const int* im = idxMap + b * cN;
  const float INF = __uint_as_float(0x7f800000u);
  const float MARGIN = 2e-3f;
  const int jA = half * 2048;              // sampled-half base
  const int jB = half * 4096;              // full-half base

  // fast coeffs (-2x,-2y,-2z) per query; q.w folded out of the scan (constant shift)
#define KNN_LOADQ(i) \
  const float4 q##i = Cb[s0 + i]; \
  const float qx##i = -2.0f * q##i.x, qy##i = -2.0f * q##i.y, qz##i = -2.0f * q##i.z;
  KNN_FORQ(KNN_LOADQ)
#undef KNN_LOADQ
  if (tid < QPB) sCnt[tid] = 0;

  // ---- Pass A: sampled half-region, per-lane fast minima (f' domain) ----
  float mn0 = INF, mn1 = INF, mn2 = INF, mn3 = INF;
  float mn4 = INF, mn5 = INF, mn6 = INF, mn7 = INF;
  #pragma unroll 4
  for (int k = 0; k < 8; k++) {
    float4 cp = Cb[jA + k * 256 + tid];
#define KNN_AMIN(i) mn##i = fminf(mn##i, fmaf(qz##i, cp.z, fmaf(qy##i, cp.y, fmaf(qx##i, cp.x, cp.w))));
    KNN_FORQ(KNN_AMIN)
#undef KNN_AMIN
  }
#define KNN_WMIN(i) tmpAll[i][tid] = mn##i;
  KNN_FORQ(KNN_WMIN)
#undef KNN_WMIN
  __syncthreads();                          // publishes tmpAll + sCnt = 0

  // ---- tau: wave wv reduces queries 2wv,2wv+1 — exact 4th-smallest of 256 lane-minima ----
  {
    const int qa = wv * 2;
    #pragma unroll
    for (int qq = 0; qq < 2; qq++) {
      float4 vq = *(const float4*)&tmpAll[qa + qq][lane * 4];
      float a0 = vq.x, a1 = vq.y, a2 = vq.z, a3 = vq.w;
      cef(a0, a1); cef(a2, a3); cef(a0, a2); cef(a1, a3); cef(a1, a2);  // sort-4 asc
      top4_merge64(a0, a1, a2, a3);
      if (lane == 0) gBuf[qa + qq] = a3 + MARGIN;
    }
  }
  __syncthreads();
  const float g0 = gBuf[0], g1 = gBuf[1], g2 = gBuf[2], g3 = gBuf[3];
  const float g4 = gBuf[4], g5 = gBuf[5], g6 = gBuf[6], g7 = gBuf[7];

  // ---- Pass B: full half-region scan, fast gate; outer hit-guard + position push ----
  #pragma unroll 2
  for (int k = 0; k < 16; k++) {
    int j = jB + k * 256 + tid;
    float4 cp = Cb[j];
#define KNN_F(i) float f##i = fmaf(qz##i, cp.z, fmaf(qy##i, cp.y, fmaf(qx##i, cp.x, cp.w)));
    KNN_FORQ(KNN_F)
#undef KNN_F
    bool hit = (f0 <= g0) | (f1 <= g1) | (f2 <= g2) | (f3 <= g3)
             | (f4 <= g4) | (f5 <= g5) | (f6 <= g6) | (f7 <= g7);
    if (hit) {
#define KNN_PUSH(i) if (f##i <= g##i) { int s = atomicAdd(&sCnt[i], 1); if (s < CAP) sPos[i][s] = j; }
      KNN_FORQ(KNN_PUSH)
#undef KNN_PUSH
    }
  }
  __syncthreads();

  // ---- final: exact keys for survivors, u64 butterfly; wave wv owns queries 2wv,2wv+1.
  // half0: modes {0,1} (its region IS the sampled set); half1: mode 0 only.
  // Raw sorted key-quads go to PT: slot 0 = half0/mode0, slot 4 = half1/mode0,
  // slot 8 = half0/mode1. Merge kernel combines.
  const ull KE = 0x7F800000FFFFFFFFull;
  const int nm = half ? 1 : 2;
  #pragma unroll
  for (int qi = 0; qi < 2; qi++) {
    const int qloc = wv * 2 + qi;
    const float4 qv = Cb[s0 + qloc];        // exact coords, L2-hot re-read
    for (int mode = 0; mode < nm; mode++) {
      int cnt = sCnt[qloc]; cnt = cnt > CAP ? CAP : cnt;
      ull k0 = KE, k1 = KE;
      if (lane < cnt) {
        int pos = sPos[qloc][lane];
        if (mode == 0 || pos < cS) {
          float4 cp = Cb[pos];
          float fe = fmaxf(d2exact_rn(qv.x, qv.y, qv.z, qv.w, cp.x, cp.y, cp.z, cp.w), 1e-12f);
          unsigned idx = mode ? (unsigned)pos : (unsigned)im[pos];
          k0 = ((ull)__float_as_uint(fe) << 32) | idx;
        }
      }
      if (lane + 64 < cnt) {
        int pos = sPos[qloc][lane + 64];
        if (mode == 0 || pos < cS) {
          float4 cp = Cb[pos];
          float fe = fmaxf(d2exact_rn(qv.x, qv.y, qv.z, qv.w, cp.x, cp.y, cp.z, cp.w), 1e-12f);
          unsigned idx = mode ? (unsigned)pos : (unsigned)im[pos];
          k1 = ((ull)__float_as_uint(fe) << 32) | idx;
        }
      }
      if (k1 < k0) { ull t = k0; k0 = k1; k1 = t; }
      ull k2 = KE, k3 = KE;
      #pragma unroll
      for (int off = 1; off < 64; off <<= 1) {
        ull b0 = __shfl_xor(k0, off, 64), b1 = __shfl_xor(k1, off, 64);
        ull b2 = __shfl_xor(k2, off, 64), b3 = __shfl_xor(k3, off, 64);
        ull m0 = k0 < b3 ? k0 : b3;
        ull m1 = k1 < b2 ? k1 : b2;
        ull m2 = k2 < b1 ? k2 : b1;
        ull m3 = k3 < b0 ? k3 : b0;
        ce64(m0, m2); ce64(m1, m3); ce64(m0, m1); ce64(m2, m3);
        k0 = m0; k1 = m1; k2 = m2; k3 = m3;
      }
      if (lane == 0) {
        ull* pt = PT + (size_t)(qbase + qloc) * 12 + (mode ? 8 : (half ? 4 : 0));
        pt[0] = k0; pt[1] = k1; pt[2] = k2; pt[3] = k3;
      }
    }
  }
}

// ---- K2b: merge the two half top-4 quads (mode0) + pass through mode1; epilogue ----
// Bitonic merge of two sorted quads: append reversed b -> bitonic 8; dist-4 clean keeps
// the 4 smallest in the lower half (bitonic); 4-elem bitonic merge sorts them. 8 ce64,
// branchless, exact same u64 comparator as the butterfly => bit-identical to full top-4.
__global__ __launch_bounds__(256) void merge_kernel(const ull* __restrict__ PT,
                                                    const int* __restrict__ idxMap,
                                                    float* __restrict__ trans,
                                                    int* __restrict__ AB,
                                                    int* __restrict__ AA) {
  int t = blockIdx.x * 256 + threadIdx.x;
  if (t >= cB * cS) return;
  const int b = t >> 12;
  const int* im = idxMap + b * cN;
  const ull* p = PT + (size_t)t * 12;

  // mode 0: merge sorted quads p[0..3] and p[4..7]
  ull v0 = p[0], v1 = p[1], v2 = p[2], v3 = p[3];
  ull v4 = p[7], v5 = p[6], v6 = p[5], v7 = p[4];   // reversed second quad
  ce64(v0, v4); ce64(v1, v5); ce64(v2, v6); ce64(v3, v7);
  ce64(v0, v2); ce64(v1, v3); ce64(v0, v1); ce64(v2, v3);
  {
    float* tr = trans + t * cTR;
    tr[0] = sqrtf(__uint_as_float((unsigned)(v1 >> 32)));
    tr[1] = sqrtf(__uint_as_float((unsigned)(v2 >> 32)));
    tr[2] = sqrtf(__uint_as_float((unsigned)(v3 >> 32)));
    int* ao = AB + t * 4;
    ao[0] = (int)(unsigned)v0; ao[1] = (int)(unsigned)v1;
    ao[2] = (int)(unsigned)v2; ao[3] = (int)(unsigned)v3;
  }
  // mode 1: half0 quad is already the exact sampled top-4 (keys carry SP pos)
  {
    ull w0 = p[8], w1 = p[9], w2 = p[10], w3 = p[11];
    float* tr = trans + t * cTR + 6;
    tr[0] = sqrtf(__uint_as_float((unsigned)(w1 >> 32)));
    tr[1] = sqrtf(__uint_as_float((unsigned)(w2 >> 32)));
    tr[2] = sqrtf(__uint_as_float((unsigned)(w3 >> 32)));
    int* ao = AA + t * 4;
    ao[0] = im[(unsigned)w0]; ao[1] = im[(unsigned)w1];
    ao[2] = im[(unsigned)w2]; ao[3] = im[(unsigned)w3];
  }
}

// ---- K3: anchor-anchor dists (intra ch3-5/9-11 + inter ch12-27) + 3-layer MLP ----
// r2-verified 4-row config (r4 lesson: 8 rows/wave -> 1 wave/SIMD, latency-exposed, +6us).
__global__ __launch_bounds__(64) void mlp_kernel(
    const float* __restrict__ TR, const float4* __restrict__ P,
    const int* __restrict__ AB, const int* __restrict__ AA,
    const float* __restrict__ feat, const int* __restrict__ smp,
    const float* __restrict__ w1, const float* __restrict__ b1,
    const float* __restrict__ g1, const float* __restrict__ be1,
    const float* __restrict__ w2, const float* __restrict__ b2,
    const float* __restrict__ g2, const float* __restrict__ be2,
    const float* __restrict__ w3, const float* __restrict__ b3,
    const float* __restrict__ g3, const float* __restrict__ be3,
    float* __restrict__ out) {
  __shared__ alignas(16) float tinT[28 * 4];
  __shared__ alignas(16) float act1T[64 * 4];
  __shared__ alignas(16) float act2T[128 * 4];   // ch 0..63 = feat, 64..127 = L2 out

  const int lane = threadIdx.x;
  const int r0 = blockIdx.x * 4;
  const int b = r0 >> 12;
  const float inv = 1.0f / sqrtf(1.0f + 1e-5f);

  float pb1 = b1[lane], pg1 = g1[lane] * inv, pe1 = be1[lane];
  float pb2 = b2[lane], pg2 = g2[lane] * inv, pe2 = be2[lane];
  float pb3a = b3[lane],      pg3a = g3[lane] * inv,      pe3a = be3[lane];
  float pb3b = b3[lane + 64], pg3b = g3[lane + 64] * inv, pe3b = be3[lane + 64];

  // stage feat -> act2T ch 0..63
  {
    const float* fb = feat + (size_t)b * cN * 64;
    float4 v;
    v.x = fb[smp[r0 + 0] * 64 + lane];
    v.y = fb[smp[r0 + 1] * 64 + lane];
    v.z = fb[smp[r0 + 2] * 64 + lane];
    v.w = fb[smp[r0 + 3] * 64 + lane];
    *(float4*)&act2T[lane * 4] = v;
  }
  // stage tinT (28ch x 4r = 112 items)
  {
    const float4* Pb = P + b * cN;
    #pragma unroll
    for (int t = 0; t < 2; t++) {
      int idx = t * 64 + lane;
      if (idx < 112) {
        int r = idx & 3, ch = idx >> 2;
        float v;
        if (ch < 3) {
          v = TR[(r0 + r) * cTR + ch];
        } else if (ch < 6) {
          int pi = (ch == 3) ? 1 : 1 + (ch - 4), pj = (ch == 3) ? 2 : 3;
          if (ch == 5) { pi = 2; pj = 3; }
          v = dist_rn4(Pb[AB[(r0 + r) * 4 + pi]], Pb[AB[(r0 + r) * 4 + pj]]);
        } else if (ch < 9) {
          v = TR[(r0 + r) * cTR + ch];
        } else if (ch < 12) {
          int cc = ch - 9;
          int pi = (cc == 0) ? 1 : ((cc == 1) ? 1 : 2);
          int pj = (cc == 0) ? 2 : 3;
          v = dist_rn4(Pb[AA[(r0 + r) * 4 + pi]], Pb[AA[(r0 + r) * 4 + pj]]);
        } else {
          int cc = ch - 12;
          int gi = AB[(r0 + r) * 4 + (cc >> 2)];
          int gj = AA[(r0 + r) * 4 + (cc & 3)];
          v = dist_rn4(Pb[gi], Pb[gj]);
        }
        tinT[ch * 4 + r] = v;
      }
    }
  }
  __syncthreads();

  // L1: 28 -> 64
  {
    float4 acc = make_float4(pb1, pb1, pb1, pb1);
    #pragma unroll 4
    for (int k = 0; k < 28; k++) {
      float w = w1[k * 64 + lane];
      float4 a = *(const float4*)&tinT[k * 4];
      acc.x = fmaf(a.x, w, acc.x); acc.y = fmaf(a.y, w, acc.y);
      acc.z = fmaf(a.z, w, acc.z); acc.w = fmaf(a.w, w, acc.w);
    }
    float4 o;
    o.x = fmaf(acc.x, pg1, pe1); o.y = fmaf(acc.y, pg1, pe1);
    o.z = fmaf(acc.z, pg1, pe1); o.w = fmaf(acc.w, pg1, pe1);
    o.x = o.x >= 0.0f ? o.x : 0.2f * o.x; o.y = o.y >= 0.0f ? o.y : 0.2f * o.y;
    o.z = o.z >= 0.0f ? o.z : 0.2f * o.z; o.w = o.w >= 0.0f ? o.w : 0.2f * o.w;
    __syncthreads();
    *(float4*)&act1T[lane * 4] = o;
  }
  __syncthreads();
  // L2: 64 -> 64
  {
    float4 acc = make_float4(pb2, pb2, pb2, pb2);
    #pragma unroll 8
    for (int k = 0; k < 64; k++) {
      float w = w2[k * 64 + lane];
      float4 a = *(const float4*)&act1T[k * 4];
      acc.x = fmaf(a.x, w, acc.x); acc.y = fmaf(a.y, w, acc.y);
      acc.z = fmaf(a.z, w, acc.z); acc.w = fmaf(a.w, w, acc.w);
    }
    float4 o;
    o.x = fmaf(acc.x, pg2, pe2); o.y = fmaf(acc.y, pg2, pe2);
    o.z = fmaf(acc.z, pg2, pe2); o.w = fmaf(acc.w, pg2, pe2);
    o.x = o.x >= 0.0f ? o.x : 0.2f * o.x; o.y = o.y >= 0.0f ? o.y : 0.2f * o.y;
    o.z = o.z >= 0.0f ? o.z : 0.2f * o.z; o.w = o.w >= 0.0f ? o.w : 0.2f * o.w;
    *(float4*)&act2T[(64 + lane) * 4] = o;
  }
  __syncthreads();
  // L3: 128 -> 128 (lane covers ch and ch+64)
  {
    float4 aA = make_float4(pb3a, pb3a, pb3a, pb3a);
    float4 aB = make_float4(pb3b, pb3b, pb3b, pb3b);
    #pragma unroll 8
    for (int k = 0; k < 128; k++) {
      float wA = w3[k * 128 + lane];
      float wB = w3[k * 128 + 64 + lane];
      float4 a = *(const float4*)&act2T[k * 4];
      aA.x = fmaf(a.x, wA, aA.x); aA.y = fmaf(a.y, wA, aA.y);
      aA.z = fmaf(a.z, wA, aA.z); aA.w = fmaf(a.w, wA, aA.w);
      aB.x = fmaf(a.x, wB, aB.x); aB.y = fmaf(a.y, wB, aB.y);
      aB.z = fmaf(a.z, wB, aB.z); aB.w = fmaf(a.w, wB, aB.w);
    }
    float rA0 = aA.x, rA1 = aA.y, rA2 = aA.z, rA3 = aA.w;
    float rB0 = aB.x, rB1 = aB.y, rB2 = aB.z, rB3 = aB.w;
    float xA, xB;
    xA = fmaf(rA0, pg3a, pe3a); xB = fmaf(rB0, pg3b, pe3b);
    xA = xA >= 0.0f ? xA : 0.2f * xA; xB = xB >= 0.0f ? xB : 0.2f * xB;
    out[(r0 + 0) * 128 + lane] = xA; out[(r0 + 0) * 128 + 64 + lane] = xB;
    xA = fmaf(rA1, pg3a, pe3a); xB = fmaf(rB1, pg3b, pe3b);
    xA = xA >= 0.0f ? xA : 0.2f * xA; xB = xB >= 0.0f ? xB : 0.2f * xB;
    out[(r0 + 1) * 128 + lane] = xA; out[(r0 + 1) * 128 + 64 + lane] = xB;
    xA = fmaf(rA2, pg3a, pe3a); xB = fmaf(rB2, pg3b, pe3b);
    xA = xA >= 0.0f ? xA : 0.2f * xA; xB = xB >= 0.0f ? xB : 0.2f * xB;
    out[(r0 + 2) * 128 + lane] = xA; out[(r0 + 2) * 128 + 64 + lane] = xB;
    xA = fmaf(rA3, pg3a, pe3a); xB = fmaf(rB3, pg3b, pe3b);
    xA = xA >= 0.0f ? xA : 0.2f * xA; xB = xB >= 0.0f ? xB : 0.2f * xB;
    out[(r0 + 3) * 128 + lane] = xA; out[(r0 + 3) * 128 + 64 + lane] = xB;
  }
}

extern "C" void kernel_launch(void* const* d_in, const int* in_sizes, int n_in,
                              void* d_out, int out_size, void* d_ws, size_t ws_size,
                              hipStream_t stream) {
  const float* xyz  = (const float*)d_in[0];
  const float* feat = (const float*)d_in[1];
  const int*   smp  = (const int*)d_in[2];
  const float* w1   = (const float*)d_in[3];
  const float* b1   = (const float*)d_in[4];
  const float* g1   = (const float*)d_in[5];
  const float* be1  = (const float*)d_in[6];
  const float* w2   = (const float*)d_in[7];
  const float* b2   = (const float*)d_in[8];
  const float* g2   = (const float*)d_in[9];
  const float* be2  = (const float*)d_in[10];
  const float* w3   = (const float*)d_in[11];
  const float* b3   = (const float*)d_in[12];
  const float* g3   = (const float*)d_in[13];
  const float* be3  = (const float*)d_in[14];
  float* out = (float*)d_out;

  char* ws = (char*)d_ws;
  float4* P      = (float4*)(ws);                 // 262144 B
  float4* P2     = (float4*)(ws + 262144);        // 262144 B
  int*    idxMap = (int*)(ws + 524288);           // 65536 B
  float*  TR     = (float*)(ws + 589824);         // B*S*12*4 = 393216 B
  int*    AB     = (int*)(ws + 983040);           // 131072 B
  int*    AA     = (int*)(ws + 1114112);          // 131072 B
  ull*    PT     = (ull*)(ws + 1245184);          // B*S*12*8 = 786432 B

  pack_kernel<<<48, 512, 0, stream>>>(xyz, smp, P, P2, idxMap, out);
  knn_kernel<<<cB * cS / QPB * 2, 256, 0, stream>>>(P2, idxMap, PT);
  merge_kernel<<<cB * cS / 256, 256, 0, stream>>>(PT, idxMap, TR, AB, AA);
  mlp_kernel<<<2048, 64, 0, stream>>>(TR, P, AB, AA, feat, smp,
                                      w1, b1, g1, be1, w2, b2, g2, be2,
                                      w3, b3, g3, be3, out + cB * cS * 3);
}

// Round 6
// 136.703 us; speedup vs baseline: 1.0866x; 1.0866x over previous
//
#include <hip/hip_runtime.h>
#include <math.h>

// Problem constants (match reference)
constexpr int cB = 2, cN = 8192, cS = 4096;
constexpr int cTR = 12;    // stored trans channels (0-5 before, 6-11 after)
constexpr int CAP = 160;   // survivor slots per query (r6: raised from 96 — subset gate is
                           // looser, expected ~16-28 survivors/query, keep 6x headroom)

typedef unsigned long long ull;

// ---- exact distance: EXACTLY mirrors reference arithmetic ----
// ref: sq = (x*x + y*y) + z*z ; d2 = (sq_i + sq_j) - 2*dot ; d = sqrt(max(d2,1e-12))
__device__ __forceinline__ float d2exact_rn(float qx, float qy, float qz, float qw,
                                            float cx, float cy, float cz, float cw) {
  float dot = __fadd_rn(__fadd_rn(__fmul_rn(qx, cx), __fmul_rn(qy, cy)), __fmul_rn(qz, cz));
  return __fsub_rn(__fadd_rn(qw, cw), __fmul_rn(2.0f, dot));
}
__device__ __forceinline__ float dist_rn4(float4 a, float4 b) {
  return sqrtf(fmaxf(d2exact_rn(a.x, a.y, a.z, a.w, b.x, b.y, b.z, b.w), 1e-12f));
}
__device__ __forceinline__ void ce64(ull& a, ull& b) {
  ull lo = a < b ? a : b;
  ull hi = a < b ? b : a;
  a = lo; b = hi;
}
__device__ __forceinline__ void cef(float& a, float& b) {
  float lo = fminf(a, b), hi = fmaxf(a, b);
  a = lo; b = hi;
}
// 6-step bitonic top-4 butterfly over 64 lanes. Input: per-lane SORTED quad a0<=a1<=a2<=a3.
// Output: all lanes hold the sorted 4 smallest of all 256 values. (Verified r2.)
__device__ __forceinline__ void top4_merge64(float& a0, float& a1, float& a2, float& a3) {
  #pragma unroll
  for (int off = 1; off < 64; off <<= 1) {
    float s0 = __shfl_xor(a0, off, 64), s1 = __shfl_xor(a1, off, 64);
    float s2 = __shfl_xor(a2, off, 64), s3 = __shfl_xor(a3, off, 64);
    float n0 = fminf(a0, s3), n1 = fminf(a1, s2), n2 = fminf(a2, s1), n3 = fminf(a3, s0);
    float t;
    t = fminf(n0, n2); n2 = fmaxf(n0, n2); n0 = t;
    t = fminf(n1, n3); n3 = fmaxf(n1, n3); n1 = t;
    t = fminf(n0, n1); n1 = fmaxf(n0, n1); n0 = t;
    t = fminf(n2, n3); n3 = fmaxf(n2, n3); n2 = t;
    a0 = n0; a1 = n1; a2 = n2; a3 = n3;
  }
}

// ---- K1: pack. P = orig order (clean sq); P2 = sampled-first permuted; idxMap -> orig ----
// smp sorted per batch: sampled rank lo via binary search; unsampled pos = cS + n - lo.
__global__ __launch_bounds__(512) void pack_kernel(const float* __restrict__ xyz,
                                                   const int* __restrict__ smp,
                                                   float4* __restrict__ P,
                                                   float4* __restrict__ P2,
                                                   int* __restrict__ idxMap,
                                                   float* __restrict__ oxyz) {
  int t = blockIdx.x * 512 + threadIdx.x;
  if (t < cB * cN) {
    int b = t >> 13, n = t & (cN - 1);
    const float* p = xyz + t * 3;
    float x = p[0], y = p[1], z = p[2];
    float sq = __fadd_rn(__fadd_rn(__fmul_rn(x, x), __fmul_rn(y, y)), __fmul_rn(z, z));
    const int* sb = smp + b * cS;
    int lo = 0, hi = cS;
    while (lo < hi) { int mid = (lo + hi) >> 1; if (sb[mid] < n) lo = mid + 1; else hi = mid; }
    bool flg = (lo < cS) && (sb[lo] == n);
    P[t] = make_float4(x, y, z, sq);
    int pos = flg ? lo : (cS + n - lo);
    int gp = b * cN + pos;
    P2[gp] = make_float4(x, y, z, sq);
    idxMap[gp] = n;
  } else if (t < cB * cN + cB * cS) {
    int j = t - cB * cN;
    int b = j >> 12;
    const float* p = xyz + (b * cN + smp[j]) * 3;
    oxyz[j * 3 + 0] = p[0]; oxyz[j * 3 + 1] = p[1]; oxyz[j * 3 + 2] = p[2];
  }
}

// ---- K2: 4-NN both modes, two-pass scan (r2-verified structure, QPB=4, 2048 blocks).
// r6 change: Pass A gate scans only sampled[0:2048] (8 iters, was 16). SUBSET-GATE
// VALIDITY (HW-verified r5): 4th-smallest of lane-minima over a SUBSET of the sampled set
// >= true 4th-NN distance in sampled >= true 4th-NN in full set, so the gate never rejects
// a true top-4 element of either mode; exactness preserved by the unchanged exact re-score
// + butterfly. Evals/thread 192 -> 160 (-17%); gate ~rank 8-14 of sampled (was ~4-7) ->
// expected survivors ~16-28/query (CAP=160 headroom). r5 lesson: half-sample gates (rank
// ~2x) + 8-way push doubled survivor cost — this is the mild version with the cheap 4-way
// push. NO per-thread candidate cache (r1: scratch spill). tau via LDS-transpose reduction
// (r2-verified). Final phase unchanged (bit-identical to reference top_k).
__global__ __launch_bounds__(256, 4) void knn_kernel(const float4* __restrict__ P2,
                                                     const int* __restrict__ idxMap,
                                                     float* __restrict__ trans,
                                                     int* __restrict__ AB,
                                                     int* __restrict__ AA) {
  __shared__ int sPos[4][CAP];
  __shared__ int sCnt[4];
  __shared__ alignas(16) float tmpAll[4][256];   // [query][tid] lane minima
  __shared__ alignas(16) float gBuf[4];

  const int tid = threadIdx.x, wv = tid >> 6, lane = tid & 63;
  const int qbase = blockIdx.x * 4;        // 4 | 4096 -> same batch
  const int b = qbase >> 12;
  const int s0 = qbase & (cS - 1);
  const float4* Cb = P2 + b * cN;
  const int* im = idxMap + b * cN;
  const float INF = __uint_as_float(0x7f800000u);
  const float MARGIN = 2e-3f;

  // fast coeffs (-2x,-2y,-2z); q.w folded out of the scan (constant shift per query)
  float4 q0 = Cb[s0 + 0], q1 = Cb[s0 + 1], q2 = Cb[s0 + 2], q3 = Cb[s0 + 3];
  const float qx0 = -2.0f * q0.x, qy0 = -2.0f * q0.y, qz0 = -2.0f * q0.z;
  const float qx1 = -2.0f * q1.x, qy1 = -2.0f * q1.y, qz1 = -2.0f * q1.z;
  const float qx2 = -2.0f * q2.x, qy2 = -2.0f * q2.y, qz2 = -2.0f * q2.z;
  const float qx3 = -2.0f * q3.x, qy3 = -2.0f * q3.y, qz3 = -2.0f * q3.z;
  if (tid < 4) sCnt[tid] = 0;

  // ---- Pass A: sampled SUBSET [0, 2048), per-lane fast minima (f' domain) ----
  float mn0 = INF, mn1 = INF, mn2 = INF, mn3 = INF;
  #pragma unroll 4
  for (int k = 0; k < 8; k++) {
    float4 cp = Cb[k * 256 + tid];
    mn0 = fminf(mn0, fmaf(qz0, cp.z, fmaf(qy0, cp.y, fmaf(qx0, cp.x, cp.w))));
    mn1 = fminf(mn1, fmaf(qz1, cp.z, fmaf(qy1, cp.y, fmaf(qx1, cp.x, cp.w))));
    mn2 = fminf(mn2, fmaf(qz2, cp.z, fmaf(qy2, cp.y, fmaf(qx2, cp.x, cp.w))));
    mn3 = fminf(mn3, fmaf(qz3, cp.z, fmaf(qy3, cp.y, fmaf(qx3, cp.x, cp.w))));
  }
  tmpAll[0][tid] = mn0;
  tmpAll[1][tid] = mn1;
  tmpAll[2][tid] = mn2;
  tmpAll[3][tid] = mn3;
  __syncthreads();                          // publishes tmpAll + sCnt = 0

  // ---- tau: wave wv reduces query wv — exact 4th-smallest of its 256 lane-minima ----
  {
    float4 vq = *(const float4*)&tmpAll[wv][lane * 4];
    float a0 = vq.x, a1 = vq.y, a2 = vq.z, a3 = vq.w;
    cef(a0, a1); cef(a2, a3); cef(a0, a2); cef(a1, a3); cef(a1, a2);  // sort-4 asc
    top4_merge64(a0, a1, a2, a3);
    if (lane == 0) gBuf[wv] = a3 + MARGIN;
  }
  __syncthreads();
  const float g0 = gBuf[0], g1 = gBuf[1], g2 = gBuf[2], g3 = gBuf[3];

  // ---- Pass B: full scan, fast gate; outer hit-guard + tiny position-push interior ----
  #pragma unroll 2
  for (int k = 0; k < 32; k++) {
    int j = k * 256 + tid;
    float4 cp = Cb[j];
    float f0 = fmaf(qz0, cp.z, fmaf(qy0, cp.y, fmaf(qx0, cp.x, cp.w)));
    float f1 = fmaf(qz1, cp.z, fmaf(qy1, cp.y, fmaf(qx1, cp.x, cp.w)));
    float f2 = fmaf(qz2, cp.z, fmaf(qy2, cp.y, fmaf(qx2, cp.x, cp.w)));
    float f3 = fmaf(qz3, cp.z, fmaf(qy3, cp.y, fmaf(qx3, cp.x, cp.w)));
    bool hit = (f0 <= g0) | (f1 <= g1) | (f2 <= g2) | (f3 <= g3);
    if (hit) {                             // skipped wholesale when no lane hits
      if (f0 <= g0) { int s = atomicAdd(&sCnt[0], 1); if (s < CAP) sPos[0][s] = j; }
      if (f1 <= g1) { int s = atomicAdd(&sCnt[1], 1); if (s < CAP) sPos[1][s] = j; }
      if (f2 <= g2) { int s = atomicAdd(&sCnt[2], 1); if (s < CAP) sPos[2][s] = j; }
      if (f3 <= g3) { int s = atomicAdd(&sCnt[3], 1); if (s < CAP) sPos[3][s] = j; }
    }
  }
  __syncthreads();

  // ---- final: exact keys for survivors, u64 butterfly per (query, mode); 8 pairs / 4 waves.
  // CAP=160 > 128: lanes cover slots {lane, lane+64, lane+128(<CAP)} -> 3 candidate keys;
  // pre-merge k0..k2 into sorted triple + KE pad, butterfly unchanged (merges sorted quads).
  const ull KE = 0x7F800000FFFFFFFFull;
  const int qloc = wv;                      // wave handles its query's two modes
  const float4 qv = Cb[s0 + qloc];          // exact coords, L2-hot re-read (no dynamic qf[])
  #pragma unroll
  for (int mode = 0; mode < 2; mode++) {
    int cnt = sCnt[qloc]; cnt = cnt > CAP ? CAP : cnt;
    ull k0 = KE, k1 = KE, kx = KE;
    if (lane < cnt) {
      int pos = sPos[qloc][lane];
      if (mode == 0 || pos < cS) {
        float4 cp = Cb[pos];
        float fe = fmaxf(d2exact_rn(qv.x, qv.y, qv.z, qv.w, cp.x, cp.y, cp.z, cp.w), 1e-12f);
        unsigned idx = mode ? (unsigned)pos : (unsigned)im[pos];
        k0 = ((ull)__float_as_uint(fe) << 32) | idx;
      }
    }
    if (lane + 64 < cnt) {
      int pos = sPos[qloc][lane + 64];
      if (mode == 0 || pos < cS) {
        float4 cp = Cb[pos];
        float fe = fmaxf(d2exact_rn(qv.x, qv.y, qv.z, qv.w, cp.x, cp.y, cp.z, cp.w), 1e-12f);
        unsigned idx = mode ? (unsigned)pos : (unsigned)im[pos];
        k1 = ((ull)__float_as_uint(fe) << 32) | idx;
      }
    }
    if (lane + 128 < cnt) {
      int pos = sPos[qloc][lane + 128];
      if (mode == 0 || pos < cS) {
        float4 cp = Cb[pos];
        float fe = fmaxf(d2exact_rn(qv.x, qv.y, qv.z, qv.w, cp.x, cp.y, cp.z, cp.w), 1e-12f);
        unsigned idx = mode ? (unsigned)pos : (unsigned)im[pos];
        kx = ((ull)__float_as_uint(fe) << 32) | idx;
      }
    }
    // sort {k0,k1,kx} ascending -> (k0,k1,k2), pad k3=KE: sorted quad for the butterfly
    ce64(k0, k1); ce64(k1, kx); ce64(k0, k1);
    ull k2 = kx, k3 = KE;
    #pragma unroll
    for (int off = 1; off < 64; off <<= 1) {
      ull b0 = __shfl_xor(k0, off, 64), b1 = __shfl_xor(k1, off, 64);
      ull b2 = __shfl_xor(k2, off, 64), b3 = __shfl_xor(k3, off, 64);
      ull m0 = k0 < b3 ? k0 : b3;
      ull m1 = k1 < b2 ? k1 : b2;
      ull m2 = k2 < b1 ? k2 : b1;
      ull m3 = k3 < b0 ? k3 : b0;
      ce64(m0, m2); ce64(m1, m3); ce64(m0, m1); ce64(m2, m3);
      k0 = m0; k1 = m1; k2 = m2; k3 = m3;
    }
    if (lane == 0) {
      int wq = qbase + qloc;
      int i0 = (int)(unsigned)k0, i1 = (int)(unsigned)k1;
      int i2 = (int)(unsigned)k2, i3 = (int)(unsigned)k3;
      float e1 = sqrtf(__uint_as_float((unsigned)(k1 >> 32)));
      float e2 = sqrtf(__uint_as_float((unsigned)(k2 >> 32)));
      float e3 = sqrtf(__uint_as_float((unsigned)(k3 >> 32)));
      float* tr = trans + wq * cTR + (mode ? 6 : 0);
      tr[0] = e1; tr[1] = e2; tr[2] = e3;
      int* ao = (mode ? AA : AB) + wq * 4;
      if (mode) { i0 = im[i0]; i1 = im[i1]; i2 = im[i2]; i3 = im[i3]; }
      ao[0] = i0; ao[1] = i1; ao[2] = i2; ao[3] = i3;
    }
  }
}

// ---- K3: anchor-anchor dists (intra ch3-5/9-11 + inter ch12-27) + 3-layer MLP ----
// r2-verified 4-row config (r4 lesson: 8 rows/wave -> 1 wave/SIMD, latency-exposed, +6us).
__global__ __launch_bounds__(64) void mlp_kernel(
    const float* __restrict__ TR, const float4* __restrict__ P,
    const int* __restrict__ AB, const int* __restrict__ AA,
    const float* __restrict__ feat, const int* __restrict__ smp,
    const float* __restrict__ w1, const float* __restrict__ b1,
    const float* __restrict__ g1, const float* __restrict__ be1,
    const float* __restrict__ w2, const float* __restrict__ b2,
    const float* __restrict__ g2, const float* __restrict__ be2,
    const float* __restrict__ w3, const float* __restrict__ b3,
    const float* __restrict__ g3, const float* __restrict__ be3,
    float* __restrict__ out) {
  __shared__ alignas(16) float tinT[28 * 4];
  __shared__ alignas(16) float act1T[64 * 4];
  __shared__ alignas(16) float act2T[128 * 4];   // ch 0..63 = feat, 64..127 = L2 out

  const int lane = threadIdx.x;
  const int r0 = blockIdx.x * 4;
  const int b = r0 >> 12;
  const float inv = 1.0f / sqrtf(1.0f + 1e-5f);

  float pb1 = b1[lane], pg1 = g1[lane] * inv, pe1 = be1[lane];
  float pb2 = b2[lane], pg2 = g2[lane] * inv, pe2 = be2[lane];
  float pb3a = b3[lane],      pg3a = g3[lane] * inv,      pe3a = be3[lane];
  float pb3b = b3[lane + 64], pg3b = g3[lane + 64] * inv, pe3b = be3[lane + 64];

  // stage feat -> act2T ch 0..63
  {
    const float* fb = feat + (size_t)b * cN * 64;
    float4 v;
    v.x = fb[smp[r0 + 0] * 64 + lane];
    v.y = fb[smp[r0 + 1] * 64 + lane];
    v.z = fb[smp[r0 + 2] * 64 + lane];
    v.w = fb[smp[r0 + 3] * 64 + lane];
    *(float4*)&act2T[lane * 4] = v;
  }
  // stage tinT (28ch x 4r = 112 items)
  {
    const float4* Pb = P + b * cN;
    #pragma unroll
    for (int t = 0; t < 2; t++) {
      int idx = t * 64 + lane;
      if (idx < 112) {
        int r = idx & 3, ch = idx >> 2;
        float v;
        if (ch < 3) {
          v = TR[(r0 + r) * cTR + ch];
        } else if (ch < 6) {
          int pi = (ch == 3) ? 1 : 1 + (ch - 4), pj = (ch == 3) ? 2 : 3;
          if (ch == 5) { pi = 2; pj = 3; }
          v = dist_rn4(Pb[AB[(r0 + r) * 4 + pi]], Pb[AB[(r0 + r) * 4 + pj]]);
        } else if (ch < 9) {
          v = TR[(r0 + r) * cTR + ch];
        } else if (ch < 12) {
          int cc = ch - 9;
          int pi = (cc == 0) ? 1 : ((cc == 1) ? 1 : 2);
          int pj = (cc == 0) ? 2 : 3;
          v = dist_rn4(Pb[AA[(r0 + r) * 4 + pi]], Pb[AA[(r0 + r) * 4 + pj]]);
        } else {
          int cc = ch - 12;
          int gi = AB[(r0 + r) * 4 + (cc >> 2)];
          int gj = AA[(r0 + r) * 4 + (cc & 3)];
          v = dist_rn4(Pb[gi], Pb[gj]);
        }
        tinT[ch * 4 + r] = v;
      }
    }
  }
  __syncthreads();

  // L1: 28 -> 64
  {
    float4 acc = make_float4(pb1, pb1, pb1, pb1);
    #pragma unroll 4
    for (int k = 0; k < 28; k++) {
      float w = w1[k * 64 + lane];
      float4 a = *(const float4*)&tinT[k * 4];
      acc.x = fmaf(a.x, w, acc.x); acc.y = fmaf(a.y, w, acc.y);
      acc.z = fmaf(a.z, w, acc.z); acc.w = fmaf(a.w, w, acc.w);
    }
    float4 o;
    o.x = fmaf(acc.x, pg1, pe1); o.y = fmaf(acc.y, pg1, pe1);
    o.z = fmaf(acc.z, pg1, pe1); o.w = fmaf(acc.w, pg1, pe1);
    o.x = o.x >= 0.0f ? o.x : 0.2f * o.x; o.y = o.y >= 0.0f ? o.y : 0.2f * o.y;
    o.z = o.z >= 0.0f ? o.z : 0.2f * o.z; o.w = o.w >= 0.0f ? o.w : 0.2f * o.w;
    __syncthreads();
    *(float4*)&act1T[lane * 4] = o;
  }
  __syncthreads();
  // L2: 64 -> 64
  {
    float4 acc = make_float4(pb2, pb2, pb2, pb2);
    #pragma unroll 8
    for (int k = 0; k < 64; k++) {
      float w = w2[k * 64 + lane];
      float4 a = *(const float4*)&act1T[k * 4];
      acc.x = fmaf(a.x, w, acc.x); acc.y = fmaf(a.y, w, acc.y);
      acc.z = fmaf(a.z, w, acc.z); acc.w = fmaf(a.w, w, acc.w);
    }
    float4 o;
    o.x = fmaf(acc.x, pg2, pe2); o.y = fmaf(acc.y, pg2, pe2);
    o.z = fmaf(acc.z, pg2, pe2); o.w = fmaf(acc.w, pg2, pe2);
    o.x = o.x >= 0.0f ? o.x : 0.2f * o.x; o.y = o.y >= 0.0f ? o.y : 0.2f * o.y;
    o.z = o.z >= 0.0f ? o.z : 0.2f * o.z; o.w = o.w >= 0.0f ? o.w : 0.2f * o.w;
    *(float4*)&act2T[(64 + lane) * 4] = o;
  }
  __syncthreads();
  // L3: 128 -> 128 (lane covers ch and ch+64)
  {
    float4 aA = make_float4(pb3a, pb3a, pb3a, pb3a);
    float4 aB = make_float4(pb3b, pb3b, pb3b, pb3b);
    #pragma unroll 8
    for (int k = 0; k < 128; k++) {
      float wA = w3[k * 128 + lane];
      float wB = w3[k * 128 + 64 + lane];
      float4 a = *(const float4*)&act2T[k * 4];
      aA.x = fmaf(a.x, wA, aA.x); aA.y = fmaf(a.y, wA, aA.y);
      aA.z = fmaf(a.z, wA, aA.z); aA.w = fmaf(a.w, wA, aA.w);
      aB.x = fmaf(a.x, wB, aB.x); aB.y = fmaf(a.y, wB, aB.y);
      aB.z = fmaf(a.z, wB, aB.z); aB.w = fmaf(a.w, wB, aB.w);
    }
    float rA0 = aA.x, rA1 = aA.y, rA2 = aA.z, rA3 = aA.w;
    float rB0 = aB.x, rB1 = aB.y, rB2 = aB.z, rB3 = aB.w;
    float xA, xB;
    xA = fmaf(rA0, pg3a, pe3a); xB = fmaf(rB0, pg3b, pe3b);
    xA = xA >= 0.0f ? xA : 0.2f * xA; xB = xB >= 0.0f ? xB : 0.2f * xB;
    out[(r0 + 0) * 128 + lane] = xA; out[(r0 + 0) * 128 + 64 + lane] = xB;
    xA = fmaf(rA1, pg3a, pe3a); xB = fmaf(rB1, pg3b, pe3b);
    xA = xA >= 0.0f ? xA : 0.2f * xA; xB = xB >= 0.0f ? xB : 0.2f * xB;
    out[(r0 + 1) * 128 + lane] = xA; out[(r0 + 1) * 128 + 64 + lane] = xB;
    xA = fmaf(rA2, pg3a, pe3a); xB = fmaf(rB2, pg3b, pe3b);
    xA = xA >= 0.0f ? xA : 0.2f * xA; xB = xB >= 0.0f ? xB : 0.2f * xB;
    out[(r0 + 2) * 128 + lane] = xA; out[(r0 + 2) * 128 + 64 + lane] = xB;
    xA = fmaf(rA3, pg3a, pe3a); xB = fmaf(rB3, pg3b, pe3b);
    xA = xA >= 0.0f ? xA : 0.2f * xA; xB = xB >= 0.0f ? xB : 0.2f * xB;
    out[(r0 + 3) * 128 + lane] = xA; out[(r0 + 3) * 128 + 64 + lane] = xB;
  }
}

extern "C" void kernel_launch(void* const* d_in, const int* in_sizes, int n_in,
                              void* d_out, int out_size, void* d_ws, size_t ws_size,
                              hipStream_t stream) {
  const float* xyz  = (const float*)d_in[0];
  const float* feat = (const float*)d_in[1];
  const int*   smp  = (const int*)d_in[2];
  const float* w1   = (const float*)d_in[3];
  const float* b1   = (const float*)d_in[4];
  const float* g1   = (const float*)d_in[5];
  const float* be1  = (const float*)d_in[6];
  const float* w2   = (const float*)d_in[7];
  const float* b2   = (const float*)d_in[8];
  const float* g2   = (const float*)d_in[9];
  const float* be2  = (const float*)d_in[10];
  const float* w3   = (const float*)d_in[11];
  const float* b3   = (const float*)d_in[12];
  const float* g3   = (const float*)d_in[13];
  const float* be3  = (const float*)d_in[14];
  float* out = (float*)d_out;

  char* ws = (char*)d_ws;
  float4* P      = (float4*)(ws);                 // 262144 B
  float4* P2     = (float4*)(ws + 262144);        // 262144 B
  int*    idxMap = (int*)(ws + 524288);           // 65536 B
  float*  TR     = (float*)(ws + 589824);         // B*S*12*4 = 393216 B
  int*    AB     = (int*)(ws + 983040);           // 131072 B
  int*    AA     = (int*)(ws + 1114112);          // 131072 B

  pack_kernel<<<48, 512, 0, stream>>>(xyz, smp, P, P2, idxMap, out);
  knn_kernel<<<2048, 256, 0, stream>>>(P2, idxMap, TR, AB, AA);
  mlp_kernel<<<2048, 64, 0, stream>>>(TR, P, AB, AA, feat, smp,
                                      w1, b1, g1, be1, w2, b2, g2, be2,
                                      w3, b3, g3, be3, out + cB * cS * 3);
}

// Round 7
// 134.233 us; speedup vs baseline: 1.1066x; 1.0184x over previous
//
#include <hip/hip_runtime.h>
#include <math.h>

// Problem constants (match reference)
constexpr int cB = 2, cN = 8192, cS = 4096;
constexpr int cTR = 12;    // stored trans channels (0-5 before, 6-11 after)
constexpr int CAP = 96;    // survivor slots per query (full-sample gate: ~12 expected)
constexpr int QPB = 8;     // queries per knn block
constexpr int TPB = 512;   // knn threads per block (8 waves) — keeps 8 waves/SIMD at QPB=8

typedef unsigned long long ull;

// ---- exact distance: EXACTLY mirrors reference arithmetic ----
// ref: sq = (x*x + y*y) + z*z ; d2 = (sq_i + sq_j) - 2*dot ; d = sqrt(max(d2,1e-12))
__device__ __forceinline__ float d2exact_rn(float qx, float qy, float qz, float qw,
                                            float cx, float cy, float cz, float cw) {
  float dot = __fadd_rn(__fadd_rn(__fmul_rn(qx, cx), __fmul_rn(qy, cy)), __fmul_rn(qz, cz));
  return __fsub_rn(__fadd_rn(qw, cw), __fmul_rn(2.0f, dot));
}
__device__ __forceinline__ float dist_rn4(float4 a, float4 b) {
  return sqrtf(fmaxf(d2exact_rn(a.x, a.y, a.z, a.w, b.x, b.y, b.z, b.w), 1e-12f));
}
__device__ __forceinline__ void ce64(ull& a, ull& b) {
  ull lo = a < b ? a : b;
  ull hi = a < b ? b : a;
  a = lo; b = hi;
}
__device__ __forceinline__ void cef(float& a, float& b) {
  float lo = fminf(a, b), hi = fmaxf(a, b);
  a = lo; b = hi;
}
// 6-step bitonic top-4 butterfly over 64 lanes. Input: per-lane SORTED quad a0<=a1<=a2<=a3.
// Output: all lanes hold the sorted 4 smallest of all 256 values. (Verified r2.)
__device__ __forceinline__ void top4_merge64(float& a0, float& a1, float& a2, float& a3) {
  #pragma unroll
  for (int off = 1; off < 64; off <<= 1) {
    float s0 = __shfl_xor(a0, off, 64), s1 = __shfl_xor(a1, off, 64);
    float s2 = __shfl_xor(a2, off, 64), s3 = __shfl_xor(a3, off, 64);
    float n0 = fminf(a0, s3), n1 = fminf(a1, s2), n2 = fminf(a2, s1), n3 = fminf(a3, s0);
    float t;
    t = fminf(n0, n2); n2 = fmaxf(n0, n2); n0 = t;
    t = fminf(n1, n3); n3 = fmaxf(n1, n3); n1 = t;
    t = fminf(n0, n1); n1 = fmaxf(n0, n1); n0 = t;
    t = fminf(n2, n3); n3 = fmaxf(n2, n3); n2 = t;
    a0 = n0; a1 = n1; a2 = n2; a3 = n3;
  }
}

// ---- K1: pack. P = orig order (clean sq); P2 = sampled-first permuted; idxMap -> orig ----
// smp sorted per batch: sampled rank lo via binary search; unsampled pos = cS + n - lo.
__global__ __launch_bounds__(512) void pack_kernel(const float* __restrict__ xyz,
                                                   const int* __restrict__ smp,
                                                   float4* __restrict__ P,
                                                   float4* __restrict__ P2,
                                                   int* __restrict__ idxMap,
                                                   float* __restrict__ oxyz) {
  int t = blockIdx.x * 512 + threadIdx.x;
  if (t < cB * cN) {
    int b = t >> 13, n = t & (cN - 1);
    const float* p = xyz + t * 3;
    float x = p[0], y = p[1], z = p[2];
    float sq = __fadd_rn(__fadd_rn(__fmul_rn(x, x), __fmul_rn(y, y)), __fmul_rn(z, z));
    const int* sb = smp + b * cS;
    int lo = 0, hi = cS;
    while (lo < hi) { int mid = (lo + hi) >> 1; if (sb[mid] < n) lo = mid + 1; else hi = mid; }
    bool flg = (lo < cS) && (sb[lo] == n);
    P[t] = make_float4(x, y, z, sq);
    int pos = flg ? lo : (cS + n - lo);
    int gp = b * cN + pos;
    P2[gp] = make_float4(x, y, z, sq);
    idxMap[gp] = n;
  } else if (t < cB * cN + cB * cS) {
    int j = t - cB * cN;
    int b = j >> 12;
    const float* p = xyz + (b * cN + smp[j]) * 3;
    oxyz[j * 3 + 0] = p[0]; oxyz[j * 3 + 1] = p[1]; oxyz[j * 3 + 2] = p[2];
  }
}

// ---- K2: 4-NN both modes. r7: QPB=8 with 512-thread blocks.
// r3 lesson: QPB=8 @ 256thr halved the grid -> 4 waves/SIMD occupancy collapse. Here
// 1024 blocks x 512 thr = 4 blocks/CU x 8 waves = 32 waves/CU = 8 waves/SIMD — SAME
// occupancy as the verified r2 config. r5 lesson: gate stays FULL-sampled (tight).
// Per-thread evals unchanged (64+128=192); per-thread VISITS halve (48 -> 24): each 16B
// candidate load amortizes over 8 queries -> candidate L2 traffic 328->164 MB and
// load/addr/loop instrs halve. NO per-thread candidate cache (r1: scratch spill); all
// per-query state NAMED scalars via macros (registers). Pass A: full sampled region,
// per-lane fast minima in folded domain f' = cp.w - 2*dot (q.w dropped: order-preserving
// per-query shift, HW-verified r1; MARGIN 2e-3 >> fold+fast rounding gap). tau: wave wv
// reduces query wv over 512 lane-minima — stride-64 conflict-free LDS reads, sort-8 ->
// two sorted quads, bitonic quad-merge (min side) -> sorted top-4, then the verified
// 6-step butterfly => EXACT 4th-smallest of 512 lane-minima. Pass B: full scan, fast
// gate, position-only push. Final: survivors get exact reference-rounded d2 + u64
// (d2bits, idx) keys -> butterfly select == reference top_k bit-identically (unchanged).
#define KNN_FORQ(M) M(0) M(1) M(2) M(3) M(4) M(5) M(6) M(7)

__global__ __launch_bounds__(512, 8) void knn_kernel(const float4* __restrict__ P2,
                                                     const int* __restrict__ idxMap,
                                                     float* __restrict__ trans,
                                                     int* __restrict__ AB,
                                                     int* __restrict__ AA) {
  __shared__ int sPos[QPB][CAP];
  __shared__ int sCnt[QPB];
  __shared__ alignas(16) float tmpAll[QPB][TPB];   // [query][tid] lane minima (16 KB)
  __shared__ alignas(16) float gBuf[QPB];

  const int tid = threadIdx.x, wv = tid >> 6, lane = tid & 63;
  const int qbase = blockIdx.x * QPB;      // 8 | 4096 -> same batch
  const int b = qbase >> 12;
  const int s0 = qbase & (cS - 1);
  const float4* Cb = P2 + b * cN;
  const int* im = idxMap + b * cN;
  const float INF = __uint_as_float(0x7f800000u);
  const float MARGIN = 2e-3f;

  // fast coeffs (-2x,-2y,-2z) per query; q.w folded out of the scan (constant shift)
#define KNN_LOADQ(i) \
  const float4 q##i = Cb[s0 + i]; \
  const float qx##i = -2.0f * q##i.x, qy##i = -2.0f * q##i.y, qz##i = -2.0f * q##i.z;
  KNN_FORQ(KNN_LOADQ)
#undef KNN_LOADQ
  if (tid < QPB) sCnt[tid] = 0;

  // ---- Pass A: full sampled region [0, cS), per-lane fast minima (f' domain) ----
  float mn0 = INF, mn1 = INF, mn2 = INF, mn3 = INF;
  float mn4 = INF, mn5 = INF, mn6 = INF, mn7 = INF;
  #pragma unroll 4
  for (int k = 0; k < 8; k++) {
    float4 cp = Cb[k * TPB + tid];
#define KNN_AMIN(i) mn##i = fminf(mn##i, fmaf(qz##i, cp.z, fmaf(qy##i, cp.y, fmaf(qx##i, cp.x, cp.w))));
    KNN_FORQ(KNN_AMIN)
#undef KNN_AMIN
  }
#define KNN_WMIN(i) tmpAll[i][tid] = mn##i;
  KNN_FORQ(KNN_WMIN)
#undef KNN_WMIN
  __syncthreads();                          // publishes tmpAll + sCnt = 0

  // ---- tau: wave wv reduces query wv — exact 4th-smallest of its 512 lane-minima ----
  {
    // stride-64 reads: consecutive lanes -> consecutive addresses, conflict-free
    float v0 = tmpAll[wv][lane +   0], v1 = tmpAll[wv][lane +  64];
    float v2 = tmpAll[wv][lane + 128], v3 = tmpAll[wv][lane + 192];
    float v4 = tmpAll[wv][lane + 256], v5 = tmpAll[wv][lane + 320];
    float v6 = tmpAll[wv][lane + 384], v7 = tmpAll[wv][lane + 448];
    // sort quads asc
    cef(v0, v1); cef(v2, v3); cef(v0, v2); cef(v1, v3); cef(v1, v2);
    cef(v4, v5); cef(v6, v7); cef(v4, v6); cef(v5, v7); cef(v5, v6);
    // bitonic merge, keep 4 smallest sorted
    float a0 = fminf(v0, v7), a1 = fminf(v1, v6), a2 = fminf(v2, v5), a3 = fminf(v3, v4);
    cef(a0, a2); cef(a1, a3); cef(a0, a1); cef(a2, a3);
    top4_merge64(a0, a1, a2, a3);
    if (lane == 0) gBuf[wv] = a3 + MARGIN;
  }
  __syncthreads();
  const float g0 = gBuf[0], g1 = gBuf[1], g2 = gBuf[2], g3 = gBuf[3];
  const float g4 = gBuf[4], g5 = gBuf[5], g6 = gBuf[6], g7 = gBuf[7];

  // ---- Pass B: full scan, fast gate; outer hit-guard + tiny position-push interior ----
  #pragma unroll 2
  for (int k = 0; k < 16; k++) {
    int j = k * TPB + tid;
    float4 cp = Cb[j];
#define KNN_F(i) float f##i = fmaf(qz##i, cp.z, fmaf(qy##i, cp.y, fmaf(qx##i, cp.x, cp.w)));
    KNN_FORQ(KNN_F)
#undef KNN_F
    bool hit = (f0 <= g0) | (f1 <= g1) | (f2 <= g2) | (f3 <= g3)
             | (f4 <= g4) | (f5 <= g5) | (f6 <= g6) | (f7 <= g7);
    if (hit) {                             // rare: skipped wholesale when no lane hits
#define KNN_PUSH(i) if (f##i <= g##i) { int s = atomicAdd(&sCnt[i], 1); if (s < CAP) sPos[i][s] = j; }
      KNN_FORQ(KNN_PUSH)
#undef KNN_PUSH
    }
  }
  __syncthreads();

  // ---- final: exact keys for survivors, u64 butterfly per (query, mode); wave wv owns
  // query wv x 2 modes = 2 butterflies/wave (same as r2). Phase unchanged (verified).
  const ull KE = 0x7F800000FFFFFFFFull;
  const int qloc = wv;
  const float4 qv = Cb[s0 + qloc];          // exact coords, L2-hot re-read
  #pragma unroll
  for (int mode = 0; mode < 2; mode++) {
    int cnt = sCnt[qloc]; cnt = cnt > CAP ? CAP : cnt;
    ull k0 = KE, k1 = KE;
    if (lane < cnt) {
      int pos = sPos[qloc][lane];
      if (mode == 0 || pos < cS) {
        float4 cp = Cb[pos];
        float fe = fmaxf(d2exact_rn(qv.x, qv.y, qv.z, qv.w, cp.x, cp.y, cp.z, cp.w), 1e-12f);
        unsigned idx = mode ? (unsigned)pos : (unsigned)im[pos];
        k0 = ((ull)__float_as_uint(fe) << 32) | idx;
      }
    }
    if (lane + 64 < cnt) {
      int pos = sPos[qloc][lane + 64];
      if (mode == 0 || pos < cS) {
        float4 cp = Cb[pos];
        float fe = fmaxf(d2exact_rn(qv.x, qv.y, qv.z, qv.w, cp.x, cp.y, cp.z, cp.w), 1e-12f);
        unsigned idx = mode ? (unsigned)pos : (unsigned)im[pos];
        k1 = ((ull)__float_as_uint(fe) << 32) | idx;
      }
    }
    if (k1 < k0) { ull t = k0; k0 = k1; k1 = t; }
    ull k2 = KE, k3 = KE;
    #pragma unroll
    for (int off = 1; off < 64; off <<= 1) {
      ull b0 = __shfl_xor(k0, off, 64), b1 = __shfl_xor(k1, off, 64);
      ull b2 = __shfl_xor(k2, off, 64), b3 = __shfl_xor(k3, off, 64);
      ull m0 = k0 < b3 ? k0 : b3;
      ull m1 = k1 < b2 ? k1 : b2;
      ull m2 = k2 < b1 ? k2 : b1;
      ull m3 = k3 < b0 ? k3 : b0;
      ce64(m0, m2); ce64(m1, m3); ce64(m0, m1); ce64(m2, m3);
      k0 = m0; k1 = m1; k2 = m2; k3 = m3;
    }
    if (lane == 0) {
      int wq = qbase + qloc;
      int i0 = (int)(unsigned)k0, i1 = (int)(unsigned)k1;
      int i2 = (int)(unsigned)k2, i3 = (int)(unsigned)k3;
      float e1 = sqrtf(__uint_as_float((unsigned)(k1 >> 32)));
      float e2 = sqrtf(__uint_as_float((unsigned)(k2 >> 32)));
      float e3 = sqrtf(__uint_as_float((unsigned)(k3 >> 32)));
      float* tr = trans + wq * cTR + (mode ? 6 : 0);
      tr[0] = e1; tr[1] = e2; tr[2] = e3;
      int* ao = (mode ? AA : AB) + wq * 4;
      if (mode) { i0 = im[i0]; i1 = im[i1]; i2 = im[i2]; i3 = im[i3]; }
      ao[0] = i0; ao[1] = i1; ao[2] = i2; ao[3] = i3;
    }
  }
}

// ---- K3: anchor-anchor dists (intra ch3-5/9-11 + inter ch12-27) + 3-layer MLP ----
// r2-verified 4-row config (r4 lesson: 8 rows/wave -> 1 wave/SIMD, latency-exposed, +6us).
__global__ __launch_bounds__(64) void mlp_kernel(
    const float* __restrict__ TR, const float4* __restrict__ P,
    const int* __restrict__ AB, const int* __restrict__ AA,
    const float* __restrict__ feat, const int* __restrict__ smp,
    const float* __restrict__ w1, const float* __restrict__ b1,
    const float* __restrict__ g1, const float* __restrict__ be1,
    const float* __restrict__ w2, const float* __restrict__ b2,
    const float* __restrict__ g2, const float* __restrict__ be2,
    const float* __restrict__ w3, const float* __restrict__ b3,
    const float* __restrict__ g3, const float* __restrict__ be3,
    float* __restrict__ out) {
  __shared__ alignas(16) float tinT[28 * 4];
  __shared__ alignas(16) float act1T[64 * 4];
  __shared__ alignas(16) float act2T[128 * 4];   // ch 0..63 = feat, 64..127 = L2 out

  const int lane = threadIdx.x;
  const int r0 = blockIdx.x * 4;
  const int b = r0 >> 12;
  const float inv = 1.0f / sqrtf(1.0f + 1e-5f);

  float pb1 = b1[lane], pg1 = g1[lane] * inv, pe1 = be1[lane];
  float pb2 = b2[lane], pg2 = g2[lane] * inv, pe2 = be2[lane];
  float pb3a = b3[lane],      pg3a = g3[lane] * inv,      pe3a = be3[lane];
  float pb3b = b3[lane + 64], pg3b = g3[lane + 64] * inv, pe3b = be3[lane + 64];

  // stage feat -> act2T ch 0..63
  {
    const float* fb = feat + (size_t)b * cN * 64;
    float4 v;
    v.x = fb[smp[r0 + 0] * 64 + lane];
    v.y = fb[smp[r0 + 1] * 64 + lane];
    v.z = fb[smp[r0 + 2] * 64 + lane];
    v.w = fb[smp[r0 + 3] * 64 + lane];
    *(float4*)&act2T[lane * 4] = v;
  }
  // stage tinT (28ch x 4r = 112 items)
  {
    const float4* Pb = P + b * cN;
    #pragma unroll
    for (int t = 0; t < 2; t++) {
      int idx = t * 64 + lane;
      if (idx < 112) {
        int r = idx & 3, ch = idx >> 2;
        float v;
        if (ch < 3) {
          v = TR[(r0 + r) * cTR + ch];
        } else if (ch < 6) {
          int pi = (ch == 3) ? 1 : 1 + (ch - 4), pj = (ch == 3) ? 2 : 3;
          if (ch == 5) { pi = 2; pj = 3; }
          v = dist_rn4(Pb[AB[(r0 + r) * 4 + pi]], Pb[AB[(r0 + r) * 4 + pj]]);
        } else if (ch < 9) {
          v = TR[(r0 + r) * cTR + ch];
        } else if (ch < 12) {
          int cc = ch - 9;
          int pi = (cc == 0) ? 1 : ((cc == 1) ? 1 : 2);
          int pj = (cc == 0) ? 2 : 3;
          v = dist_rn4(Pb[AA[(r0 + r) * 4 + pi]], Pb[AA[(r0 + r) * 4 + pj]]);
        } else {
          int cc = ch - 12;
          int gi = AB[(r0 + r) * 4 + (cc >> 2)];
          int gj = AA[(r0 + r) * 4 + (cc & 3)];
          v = dist_rn4(Pb[gi], Pb[gj]);
        }
        tinT[ch * 4 + r] = v;
      }
    }
  }
  __syncthreads();

  // L1: 28 -> 64
  {
    float4 acc = make_float4(pb1, pb1, pb1, pb1);
    #pragma unroll 4
    for (int k = 0; k < 28; k++) {
      float w = w1[k * 64 + lane];
      float4 a = *(const float4*)&tinT[k * 4];
      acc.x = fmaf(a.x, w, acc.x); acc.y = fmaf(a.y, w, acc.y);
      acc.z = fmaf(a.z, w, acc.z); acc.w = fmaf(a.w, w, acc.w);
    }
    float4 o;
    o.x = fmaf(acc.x, pg1, pe1); o.y = fmaf(acc.y, pg1, pe1);
    o.z = fmaf(acc.z, pg1, pe1); o.w = fmaf(acc.w, pg1, pe1);
    o.x = o.x >= 0.0f ? o.x : 0.2f * o.x; o.y = o.y >= 0.0f ? o.y : 0.2f * o.y;
    o.z = o.z >= 0.0f ? o.z : 0.2f * o.z; o.w = o.w >= 0.0f ? o.w : 0.2f * o.w;
    __syncthreads();
    *(float4*)&act1T[lane * 4] = o;
  }
  __syncthreads();
  // L2: 64 -> 64
  {
    float4 acc = make_float4(pb2, pb2, pb2, pb2);
    #pragma unroll 8
    for (int k = 0; k < 64; k++) {
      float w = w2[k * 64 + lane];
      float4 a = *(const float4*)&act1T[k * 4];
      acc.x = fmaf(a.x, w, acc.x); acc.y = fmaf(a.y, w, acc.y);
      acc.z = fmaf(a.z, w, acc.z); acc.w = fmaf(a.w, w, acc.w);
    }
    float4 o;
    o.x = fmaf(acc.x, pg2, pe2); o.y = fmaf(acc.y, pg2, pe2);
    o.z = fmaf(acc.z, pg2, pe2); o.w = fmaf(acc.w, pg2, pe2);
    o.x = o.x >= 0.0f ? o.x : 0.2f * o.x; o.y = o.y >= 0.0f ? o.y : 0.2f * o.y;
    o.z = o.z >= 0.0f ? o.z : 0.2f * o.z; o.w = o.w >= 0.0f ? o.w : 0.2f * o.w;
    *(float4*)&act2T[(64 + lane) * 4] = o;
  }
  __syncthreads();
  // L3: 128 -> 128 (lane covers ch and ch+64)
  {
    float4 aA = make_float4(pb3a, pb3a, pb3a, pb3a);
    float4 aB = make_float4(pb3b, pb3b, pb3b, pb3b);
    #pragma unroll 8
    for (int k = 0; k < 128; k++) {
      float wA = w3[k * 128 + lane];
      float wB = w3[k * 128 + 64 + lane];
      float4 a = *(const float4*)&act2T[k * 4];
      aA.x = fmaf(a.x, wA, aA.x); aA.y = fmaf(a.y, wA, aA.y);
      aA.z = fmaf(a.z, wA, aA.z); aA.w = fmaf(a.w, wA, aA.w);
      aB.x = fmaf(a.x, wB, aB.x); aB.y = fmaf(a.y, wB, aB.y);
      aB.z = fmaf(a.z, wB, aB.z); aB.w = fmaf(a.w, wB, aB.w);
    }
    float rA0 = aA.x, rA1 = aA.y, rA2 = aA.z, rA3 = aA.w;
    float rB0 = aB.x, rB1 = aB.y, rB2 = aB.z, rB3 = aB.w;
    float xA, xB;
    xA = fmaf(rA0, pg3a, pe3a); xB = fmaf(rB0, pg3b, pe3b);
    xA = xA >= 0.0f ? xA : 0.2f * xA; xB = xB >= 0.0f ? xB : 0.2f * xB;
    out[(r0 + 0) * 128 + lane] = xA; out[(r0 + 0) * 128 + 64 + lane] = xB;
    xA = fmaf(rA1, pg3a, pe3a); xB = fmaf(rB1, pg3b, pe3b);
    xA = xA >= 0.0f ? xA : 0.2f * xA; xB = xB >= 0.0f ? xB : 0.2f * xB;
    out[(r0 + 1) * 128 + lane] = xA; out[(r0 + 1) * 128 + 64 + lane] = xB;
    xA = fmaf(rA2, pg3a, pe3a); xB = fmaf(rB2, pg3b, pe3b);
    xA = xA >= 0.0f ? xA : 0.2f * xA; xB = xB >= 0.0f ? xB : 0.2f * xB;
    out[(r0 + 2) * 128 + lane] = xA; out[(r0 + 2) * 128 + 64 + lane] = xB;
    xA = fmaf(rA3, pg3a, pe3a); xB = fmaf(rB3, pg3b, pe3b);
    xA = xA >= 0.0f ? xA : 0.2f * xA; xB = xB >= 0.0f ? xB : 0.2f * xB;
    out[(r0 + 3) * 128 + lane] = xA; out[(r0 + 3) * 128 + 64 + lane] = xB;
  }
}

extern "C" void kernel_launch(void* const* d_in, const int* in_sizes, int n_in,
                              void* d_out, int out_size, void* d_ws, size_t ws_size,
                              hipStream_t stream) {
  const float* xyz  = (const float*)d_in[0];
  const float* feat = (const float*)d_in[1];
  const int*   smp  = (const int*)d_in[2];
  const float* w1   = (const float*)d_in[3];
  const float* b1   = (const float*)d_in[4];
  const float* g1   = (const float*)d_in[5];
  const float* be1  = (const float*)d_in[6];
  const float* w2   = (const float*)d_in[7];
  const float* b2   = (const float*)d_in[8];
  const float* g2   = (const float*)d_in[9];
  const float* be2  = (const float*)d_in[10];
  const float* w3   = (const float*)d_in[11];
  const float* b3   = (const float*)d_in[12];
  const float* g3   = (const float*)d_in[13];
  const float* be3  = (const float*)d_in[14];
  float* out = (float*)d_out;

  char* ws = (char*)d_ws;
  float4* P      = (float4*)(ws);                 // 262144 B
  float4* P2     = (float4*)(ws + 262144);        // 262144 B
  int*    idxMap = (int*)(ws + 524288);           // 65536 B
  float*  TR     = (float*)(ws + 589824);         // B*S*12*4 = 393216 B
  int*    AB     = (int*)(ws + 983040);           // 131072 B
  int*    AA     = (int*)(ws + 1114112);          // 131072 B

  pack_kernel<<<48, 512, 0, stream>>>(xyz, smp, P, P2, idxMap, out);
  knn_kernel<<<cB * cS / QPB, TPB, 0, stream>>>(P2, idxMap, TR, AB, AA);
  mlp_kernel<<<2048, 64, 0, stream>>>(TR, P, AB, AA, feat, smp,
                                      w1, b1, g1, be1, w2, b2, g2, be2,
                                      w3, b3, g3, be3, out + cB * cS * 3);
}

// Round 8
// 131.727 us; speedup vs baseline: 1.1276x; 1.0190x over previous
//
#include <hip/hip_runtime.h>
#include <math.h>

// Problem constants (match reference)
constexpr int cB = 2, cN = 8192, cS = 4096;
constexpr int cTR = 12;    // stored trans channels (0-5 before, 6-11 after)
constexpr int CAP = 96;    // survivor slots per query (full-sample gate: ~12 expected)
constexpr int QPB = 8;     // queries per knn block
constexpr int TPB = 512;   // knn threads per block (8 waves) — keeps 8 waves/SIMD at QPB=8

typedef unsigned long long ull;

// ---- exact distance: EXACTLY mirrors reference arithmetic ----
// ref: sq = (x*x + y*y) + z*z ; d2 = (sq_i + sq_j) - 2*dot ; d = sqrt(max(d2,1e-12))
__device__ __forceinline__ float d2exact_rn(float qx, float qy, float qz, float qw,
                                            float cx, float cy, float cz, float cw) {
  float dot = __fadd_rn(__fadd_rn(__fmul_rn(qx, cx), __fmul_rn(qy, cy)), __fmul_rn(qz, cz));
  return __fsub_rn(__fadd_rn(qw, cw), __fmul_rn(2.0f, dot));
}
__device__ __forceinline__ float dist_rn4(float4 a, float4 b) {
  return sqrtf(fmaxf(d2exact_rn(a.x, a.y, a.z, a.w, b.x, b.y, b.z, b.w), 1e-12f));
}
__device__ __forceinline__ void ce64(ull& a, ull& b) {
  ull lo = a < b ? a : b;
  ull hi = a < b ? b : a;
  a = lo; b = hi;
}
__device__ __forceinline__ void cef(float& a, float& b) {
  float lo = fminf(a, b), hi = fmaxf(a, b);
  a = lo; b = hi;
}
// 6-step bitonic top-4 butterfly over 64 lanes. Input: per-lane SORTED quad a0<=a1<=a2<=a3.
// Output: all lanes hold the sorted 4 smallest of all 256 values. (Verified r2.)
__device__ __forceinline__ void top4_merge64(float& a0, float& a1, float& a2, float& a3) {
  #pragma unroll
  for (int off = 1; off < 64; off <<= 1) {
    float s0 = __shfl_xor(a0, off, 64), s1 = __shfl_xor(a1, off, 64);
    float s2 = __shfl_xor(a2, off, 64), s3 = __shfl_xor(a3, off, 64);
    float n0 = fminf(a0, s3), n1 = fminf(a1, s2), n2 = fminf(a2, s1), n3 = fminf(a3, s0);
    float t;
    t = fminf(n0, n2); n2 = fmaxf(n0, n2); n0 = t;
    t = fminf(n1, n3); n3 = fmaxf(n1, n3); n1 = t;
    t = fminf(n0, n1); n1 = fmaxf(n0, n1); n0 = t;
    t = fminf(n2, n3); n3 = fmaxf(n2, n3); n2 = t;
    a0 = n0; a1 = n1; a2 = n2; a3 = n3;
  }
}

// ---- K1: pack. P = orig order (clean sq); P2 = sampled-first permuted; idxMap -> orig ----
// smp sorted per batch: sampled rank lo via binary search; unsampled pos = cS + n - lo.
__global__ __launch_bounds__(512) void pack_kernel(const float* __restrict__ xyz,
                                                   const int* __restrict__ smp,
                                                   float4* __restrict__ P,
                                                   float4* __restrict__ P2,
                                                   int* __restrict__ idxMap,
                                                   float* __restrict__ oxyz) {
  int t = blockIdx.x * 512 + threadIdx.x;
  if (t < cB * cN) {
    int b = t >> 13, n = t & (cN - 1);
    const float* p = xyz + t * 3;
    float x = p[0], y = p[1], z = p[2];
    float sq = __fadd_rn(__fadd_rn(__fmul_rn(x, x), __fmul_rn(y, y)), __fmul_rn(z, z));
    const int* sb = smp + b * cS;
    int lo = 0, hi = cS;
    while (lo < hi) { int mid = (lo + hi) >> 1; if (sb[mid] < n) lo = mid + 1; else hi = mid; }
    bool flg = (lo < cS) && (sb[lo] == n);
    P[t] = make_float4(x, y, z, sq);
    int pos = flg ? lo : (cS + n - lo);
    int gp = b * cN + pos;
    P2[gp] = make_float4(x, y, z, sq);
    idxMap[gp] = n;
  } else if (t < cB * cN + cB * cS) {
    int j = t - cB * cN;
    int b = j >> 12;
    const float* p = xyz + (b * cN + smp[j]) * 3;
    oxyz[j * 3 + 0] = p[0]; oxyz[j * 3 + 1] = p[1]; oxyz[j * 3 + 2] = p[2];
  }
}

// ---- K2: 4-NN both modes. r7-verified config (equal-best 134.2): QPB=8, 512-thr blocks,
// 1024 blocks = 8 waves/SIMD, full-sample gate, folded f' domain, LDS-transpose tau,
// exact re-score + u64 butterfly (bit-identical to reference top_k). UNCHANGED this round.
#define KNN_FORQ(M) M(0) M(1) M(2) M(3) M(4) M(5) M(6) M(7)

__global__ __launch_bounds__(512, 8) void knn_kernel(const float4* __restrict__ P2,
                                                     const int* __restrict__ idxMap,
                                                     float* __restrict__ trans,
                                                     int* __restrict__ AB,
                                                     int* __restrict__ AA) {
  __shared__ int sPos[QPB][CAP];
  __shared__ int sCnt[QPB];
  __shared__ alignas(16) float tmpAll[QPB][TPB];   // [query][tid] lane minima (16 KB)
  __shared__ alignas(16) float gBuf[QPB];

  const int tid = threadIdx.x, wv = tid >> 6, lane = tid & 63;
  const int qbase = blockIdx.x * QPB;      // 8 | 4096 -> same batch
  const int b = qbase >> 12;
  const int s0 = qbase & (cS - 1);
  const float4* Cb = P2 + b * cN;
  const int* im = idxMap + b * cN;
  const float INF = __uint_as_float(0x7f800000u);
  const float MARGIN = 2e-3f;

  // fast coeffs (-2x,-2y,-2z) per query; q.w folded out of the scan (constant shift)
#define KNN_LOADQ(i) \
  const float4 q##i = Cb[s0 + i]; \
  const float qx##i = -2.0f * q##i.x, qy##i = -2.0f * q##i.y, qz##i = -2.0f * q##i.z;
  KNN_FORQ(KNN_LOADQ)
#undef KNN_LOADQ
  if (tid < QPB) sCnt[tid] = 0;

  // ---- Pass A: full sampled region [0, cS), per-lane fast minima (f' domain) ----
  float mn0 = INF, mn1 = INF, mn2 = INF, mn3 = INF;
  float mn4 = INF, mn5 = INF, mn6 = INF, mn7 = INF;
  #pragma unroll 4
  for (int k = 0; k < 8; k++) {
    float4 cp = Cb[k * TPB + tid];
#define KNN_AMIN(i) mn##i = fminf(mn##i, fmaf(qz##i, cp.z, fmaf(qy##i, cp.y, fmaf(qx##i, cp.x, cp.w))));
    KNN_FORQ(KNN_AMIN)
#undef KNN_AMIN
  }
#define KNN_WMIN(i) tmpAll[i][tid] = mn##i;
  KNN_FORQ(KNN_WMIN)
#undef KNN_WMIN
  __syncthreads();                          // publishes tmpAll + sCnt = 0

  // ---- tau: wave wv reduces query wv — exact 4th-smallest of its 512 lane-minima ----
  {
    // stride-64 reads: consecutive lanes -> consecutive addresses, conflict-free
    float v0 = tmpAll[wv][lane +   0], v1 = tmpAll[wv][lane +  64];
    float v2 = tmpAll[wv][lane + 128], v3 = tmpAll[wv][lane + 192];
    float v4 = tmpAll[wv][lane + 256], v5 = tmpAll[wv][lane + 320];
    float v6 = tmpAll[wv][lane + 384], v7 = tmpAll[wv][lane + 448];
    // sort quads asc
    cef(v0, v1); cef(v2, v3); cef(v0, v2); cef(v1, v3); cef(v1, v2);
    cef(v4, v5); cef(v6, v7); cef(v4, v6); cef(v5, v7); cef(v5, v6);
    // bitonic merge, keep 4 smallest sorted
    float a0 = fminf(v0, v7), a1 = fminf(v1, v6), a2 = fminf(v2, v5), a3 = fminf(v3, v4);
    cef(a0, a2); cef(a1, a3); cef(a0, a1); cef(a2, a3);
    top4_merge64(a0, a1, a2, a3);
    if (lane == 0) gBuf[wv] = a3 + MARGIN;
  }
  __syncthreads();
  const float g0 = gBuf[0], g1 = gBuf[1], g2 = gBuf[2], g3 = gBuf[3];
  const float g4 = gBuf[4], g5 = gBuf[5], g6 = gBuf[6], g7 = gBuf[7];

  // ---- Pass B: full scan, fast gate; outer hit-guard + tiny position-push interior ----
  #pragma unroll 2
  for (int k = 0; k < 16; k++) {
    int j = k * TPB + tid;
    float4 cp = Cb[j];
#define KNN_F(i) float f##i = fmaf(qz##i, cp.z, fmaf(qy##i, cp.y, fmaf(qx##i, cp.x, cp.w)));
    KNN_FORQ(KNN_F)
#undef KNN_F
    bool hit = (f0 <= g0) | (f1 <= g1) | (f2 <= g2) | (f3 <= g3)
             | (f4 <= g4) | (f5 <= g5) | (f6 <= g6) | (f7 <= g7);
    if (hit) {                             // rare: skipped wholesale when no lane hits
#define KNN_PUSH(i) if (f##i <= g##i) { int s = atomicAdd(&sCnt[i], 1); if (s < CAP) sPos[i][s] = j; }
      KNN_FORQ(KNN_PUSH)
#undef KNN_PUSH
    }
  }
  __syncthreads();

  // ---- final: exact keys for survivors, u64 butterfly per (query, mode); wave wv owns
  // query wv x 2 modes = 2 butterflies/wave. Phase unchanged (verified).
  const ull KE = 0x7F800000FFFFFFFFull;
  const int qloc = wv;
  const float4 qv = Cb[s0 + qloc];          // exact coords, L2-hot re-read
  #pragma unroll
  for (int mode = 0; mode < 2; mode++) {
    int cnt = sCnt[qloc]; cnt = cnt > CAP ? CAP : cnt;
    ull k0 = KE, k1 = KE;
    if (lane < cnt) {
      int pos = sPos[qloc][lane];
      if (mode == 0 || pos < cS) {
        float4 cp = Cb[pos];
        float fe = fmaxf(d2exact_rn(qv.x, qv.y, qv.z, qv.w, cp.x, cp.y, cp.z, cp.w), 1e-12f);
        unsigned idx = mode ? (unsigned)pos : (unsigned)im[pos];
        k0 = ((ull)__float_as_uint(fe) << 32) | idx;
      }
    }
    if (lane + 64 < cnt) {
      int pos = sPos[qloc][lane + 64];
      if (mode == 0 || pos < cS) {
        float4 cp = Cb[pos];
        float fe = fmaxf(d2exact_rn(qv.x, qv.y, qv.z, qv.w, cp.x, cp.y, cp.z, cp.w), 1e-12f);
        unsigned idx = mode ? (unsigned)pos : (unsigned)im[pos];
        k1 = ((ull)__float_as_uint(fe) << 32) | idx;
      }
    }
    if (k1 < k0) { ull t = k0; k0 = k1; k1 = t; }
    ull k2 = KE, k3 = KE;
    #pragma unroll
    for (int off = 1; off < 64; off <<= 1) {
      ull b0 = __shfl_xor(k0, off, 64), b1 = __shfl_xor(k1, off, 64);
      ull b2 = __shfl_xor(k2, off, 64), b3 = __shfl_xor(k3, off, 64);
      ull m0 = k0 < b3 ? k0 : b3;
      ull m1 = k1 < b2 ? k1 : b2;
      ull m2 = k2 < b1 ? k2 : b1;
      ull m3 = k3 < b0 ? k3 : b0;
      ce64(m0, m2); ce64(m1, m3); ce64(m0, m1); ce64(m2, m3);
      k0 = m0; k1 = m1; k2 = m2; k3 = m3;
    }
    if (lane == 0) {
      int wq = qbase + qloc;
      int i0 = (int)(unsigned)k0, i1 = (int)(unsigned)k1;
      int i2 = (int)(unsigned)k2, i3 = (int)(unsigned)k3;
      float e1 = sqrtf(__uint_as_float((unsigned)(k1 >> 32)));
      float e2 = sqrtf(__uint_as_float((unsigned)(k2 >> 32)));
      float e3 = sqrtf(__uint_as_float((unsigned)(k3 >> 32)));
      float* tr = trans + wq * cTR + (mode ? 6 : 0);
      tr[0] = e1; tr[1] = e2; tr[2] = e3;
      int* ao = (mode ? AA : AB) + wq * 4;
      if (mode) { i0 = im[i0]; i1 = im[i1]; i2 = im[i2]; i3 = im[i3]; }
      ao[0] = i0; ao[1] = i1; ao[2] = i2; ao[3] = i3;
    }
  }
}

// ---- K3: anchor-anchor dists + 3-layer MLP. r8: split-K across 2 waves.
// Mechanism: mlp is weight-load-latency-bound at 2 waves/SIMD (r4: halving waves cost
// +6us). 128-thr blocks (2 waves), grid 2048 unchanged -> 16 waves/CU = 4/SIMD (2x).
// Each wave accumulates its k-half (L1:14, L2:32, L3:64 iters); per-block weight traffic
// UNCHANGED (each wave reads only its k-range). Partials via part[2][8][64] (lane-stride-1,
// conflict-free scalar LDS); combine split by wave (rows 2w,2w+1) so both waves stay busy.
// Numerics: (b + sum_lo) + sum_hi vs b + sum — O(1e-4) perturbation, inside tolerance.
__global__ __launch_bounds__(128, 4) void mlp_kernel(
    const float* __restrict__ TR, const float4* __restrict__ P,
    const int* __restrict__ AB, const int* __restrict__ AA,
    const float* __restrict__ feat, const int* __restrict__ smp,
    const float* __restrict__ w1, const float* __restrict__ b1,
    const float* __restrict__ g1, const float* __restrict__ be1,
    const float* __restrict__ w2, const float* __restrict__ b2,
    const float* __restrict__ g2, const float* __restrict__ be2,
    const float* __restrict__ w3, const float* __restrict__ b3,
    const float* __restrict__ g3, const float* __restrict__ be3,
    float* __restrict__ out) {
  __shared__ alignas(16) float tinT[28 * 4];
  __shared__ alignas(16) float act1T[64 * 4];
  __shared__ alignas(16) float act2T[128 * 4];   // ch 0..63 = feat, 64..127 = L2 out
  __shared__ alignas(16) float part[2][8][64];   // [wave][acc-slot][lane] partials

  const int tid = threadIdx.x;
  const int lane = tid & 63, w = tid >> 6;
  const int r0 = blockIdx.x * 4;
  const int b = r0 >> 12;
  const float inv = 1.0f / sqrtf(1.0f + 1e-5f);

  float pb1 = b1[lane], pg1 = g1[lane] * inv, pe1 = be1[lane];
  float pb2 = b2[lane], pg2 = g2[lane] * inv, pe2 = be2[lane];
  float pb3a = b3[lane],      pg3a = g3[lane] * inv,      pe3a = be3[lane];
  float pb3b = b3[lane + 64], pg3b = g3[lane + 64] * inv, pe3b = be3[lane + 64];

  // stage feat -> act2T ch 0..63: thread handles ch=lane, rows {2w, 2w+1}
  {
    const float* fb = feat + (size_t)b * cN * 64;
    float2 v;
    v.x = fb[smp[r0 + 2 * w + 0] * 64 + lane];
    v.y = fb[smp[r0 + 2 * w + 1] * 64 + lane];
    *(float2*)&act2T[lane * 4 + 2 * w] = v;
  }
  // stage tinT (28ch x 4r = 112 items): 128 threads, single pass
  {
    const float4* Pb = P + b * cN;
    int idx = tid;
    if (idx < 112) {
      int r = idx & 3, ch = idx >> 2;
      float v;
      if (ch < 3) {
        v = TR[(r0 + r) * cTR + ch];
      } else if (ch < 6) {
        int pi = (ch == 3) ? 1 : 1 + (ch - 4), pj = (ch == 3) ? 2 : 3;
        if (ch == 5) { pi = 2; pj = 3; }
        v = dist_rn4(Pb[AB[(r0 + r) * 4 + pi]], Pb[AB[(r0 + r) * 4 + pj]]);
      } else if (ch < 9) {
        v = TR[(r0 + r) * cTR + ch];
      } else if (ch < 12) {
        int cc = ch - 9;
        int pi = (cc == 0) ? 1 : ((cc == 1) ? 1 : 2);
        int pj = (cc == 0) ? 2 : 3;
        v = dist_rn4(Pb[AA[(r0 + r) * 4 + pi]], Pb[AA[(r0 + r) * 4 + pj]]);
      } else {
        int cc = ch - 12;
        int gi = AB[(r0 + r) * 4 + (cc >> 2)];
        int gj = AA[(r0 + r) * 4 + (cc & 3)];
        v = dist_rn4(Pb[gi], Pb[gj]);
      }
      tinT[ch * 4 + r] = v;
    }
  }
  __syncthreads();

  // L1: 28 -> 64, k-split [14w, 14w+14)
  {
    float4 acc = (w == 0) ? make_float4(pb1, pb1, pb1, pb1)
                          : make_float4(0.f, 0.f, 0.f, 0.f);
    #pragma unroll 7
    for (int k = 14 * w; k < 14 * w + 14; k++) {
      float ww = w1[k * 64 + lane];
      float4 a = *(const float4*)&tinT[k * 4];
      acc.x = fmaf(a.x, ww, acc.x); acc.y = fmaf(a.y, ww, acc.y);
      acc.z = fmaf(a.z, ww, acc.z); acc.w = fmaf(a.w, ww, acc.w);
    }
    part[w][0][lane] = acc.x; part[w][1][lane] = acc.y;
    part[w][2][lane] = acc.z; part[w][3][lane] = acc.w;
    __syncthreads();
    // combine: wave w handles rows 2w, 2w+1
    int rA = 2 * w, rB = 2 * w + 1;
    float oA = part[0][rA][lane] + part[1][rA][lane];
    float oB = part[0][rB][lane] + part[1][rB][lane];
    oA = fmaf(oA, pg1, pe1); oB = fmaf(oB, pg1, pe1);
    oA = oA >= 0.0f ? oA : 0.2f * oA; oB = oB >= 0.0f ? oB : 0.2f * oB;
    __syncthreads();                      // part reuse guard
    act1T[lane * 4 + rA] = oA;
    act1T[lane * 4 + rB] = oB;
  }
  __syncthreads();
  // L2: 64 -> 64, k-split [32w, 32w+32)
  {
    float4 acc = (w == 0) ? make_float4(pb2, pb2, pb2, pb2)
                          : make_float4(0.f, 0.f, 0.f, 0.f);
    #pragma unroll 8
    for (int k = 32 * w; k < 32 * w + 32; k++) {
      float ww = w2[k * 64 + lane];
      float4 a = *(const float4*)&act1T[k * 4];
      acc.x = fmaf(a.x, ww, acc.x); acc.y = fmaf(a.y, ww, acc.y);
      acc.z = fmaf(a.z, ww, acc.z); acc.w = fmaf(a.w, ww, acc.w);
    }
    part[w][0][lane] = acc.x; part[w][1][lane] = acc.y;
    part[w][2][lane] = acc.z; part[w][3][lane] = acc.w;
    __syncthreads();
    int rA = 2 * w, rB = 2 * w + 1;
    float oA = part[0][rA][lane] + part[1][rA][lane];
    float oB = part[0][rB][lane] + part[1][rB][lane];
    oA = fmaf(oA, pg2, pe2); oB = fmaf(oB, pg2, pe2);
    oA = oA >= 0.0f ? oA : 0.2f * oA; oB = oB >= 0.0f ? oB : 0.2f * oB;
    __syncthreads();                      // part reuse guard
    act2T[(64 + lane) * 4 + rA] = oA;
    act2T[(64 + lane) * 4 + rB] = oB;
  }
  __syncthreads();
  // L3: 128 -> 128 (lane covers ch and ch+64), k-split [64w, 64w+64)
  {
    float4 aA = (w == 0) ? make_float4(pb3a, pb3a, pb3a, pb3a)
                         : make_float4(0.f, 0.f, 0.f, 0.f);
    float4 aB = (w == 0) ? make_float4(pb3b, pb3b, pb3b, pb3b)
                         : make_float4(0.f, 0.f, 0.f, 0.f);
    #pragma unroll 8
    for (int k = 64 * w; k < 64 * w + 64; k++) {
      float wA = w3[k * 128 + lane];
      float wB = w3[k * 128 + 64 + lane];
      float4 a = *(const float4*)&act2T[k * 4];
      aA.x = fmaf(a.x, wA, aA.x); aA.y = fmaf(a.y, wA, aA.y);
      aA.z = fmaf(a.z, wA, aA.z); aA.w = fmaf(a.w, wA, aA.w);
      aB.x = fmaf(a.x, wB, aB.x); aB.y = fmaf(a.y, wB, aB.y);
      aB.z = fmaf(a.z, wB, aB.z); aB.w = fmaf(a.w, wB, aB.w);
    }
    part[w][0][lane] = aA.x; part[w][1][lane] = aA.y;
    part[w][2][lane] = aA.z; part[w][3][lane] = aA.w;
    part[w][4][lane] = aB.x; part[w][5][lane] = aB.y;
    part[w][6][lane] = aB.z; part[w][7][lane] = aB.w;
    __syncthreads();
    // combine + store: wave w handles rows 2w, 2w+1 for both channel halves
    int rA = 2 * w, rB = 2 * w + 1;
    float sA0 = part[0][rA][lane]     + part[1][rA][lane];
    float sA1 = part[0][rB][lane]     + part[1][rB][lane];
    float sB0 = part[0][4 + rA][lane] + part[1][4 + rA][lane];
    float sB1 = part[0][4 + rB][lane] + part[1][4 + rB][lane];
    float xA, xB;
    xA = fmaf(sA0, pg3a, pe3a); xB = fmaf(sB0, pg3b, pe3b);
    xA = xA >= 0.0f ? xA : 0.2f * xA; xB = xB >= 0.0f ? xB : 0.2f * xB;
    out[(r0 + rA) * 128 + lane] = xA; out[(r0 + rA) * 128 + 64 + lane] = xB;
    xA = fmaf(sA1, pg3a, pe3a); xB = fmaf(sB1, pg3b, pe3b);
    xA = xA >= 0.0f ? xA : 0.2f * xA; xB = xB >= 0.0f ? xB : 0.2f * xB;
    out[(r0 + rB) * 128 + lane] = xA; out[(r0 + rB) * 128 + 64 + lane] = xB;
  }
}

extern "C" void kernel_launch(void* const* d_in, const int* in_sizes, int n_in,
                              void* d_out, int out_size, void* d_ws, size_t ws_size,
                              hipStream_t stream) {
  const float* xyz  = (const float*)d_in[0];
  const float* feat = (const float*)d_in[1];
  const int*   smp  = (const int*)d_in[2];
  const float* w1   = (const float*)d_in[3];
  const float* b1   = (const float*)d_in[4];
  const float* g1   = (const float*)d_in[5];
  const float* be1  = (const float*)d_in[6];
  const float* w2   = (const float*)d_in[7];
  const float* b2   = (const float*)d_in[8];
  const float* g2   = (const float*)d_in[9];
  const float* be2  = (const float*)d_in[10];
  const float* w3   = (const float*)d_in[11];
  const float* b3   = (const float*)d_in[12];
  const float* g3   = (const float*)d_in[13];
  const float* be3  = (const float*)d_in[14];
  float* out = (float*)d_out;

  char* ws = (char*)d_ws;
  float4* P      = (float4*)(ws);                 // 262144 B
  float4* P2     = (float4*)(ws + 262144);        // 262144 B
  int*    idxMap = (int*)(ws + 524288);           // 65536 B
  float*  TR     = (float*)(ws + 589824);         // B*S*12*4 = 393216 B
  int*    AB     = (int*)(ws + 983040);           // 131072 B
  int*    AA     = (int*)(ws + 1114112);          // 131072 B

  pack_kernel<<<48, 512, 0, stream>>>(xyz, smp, P, P2, idxMap, out);
  knn_kernel<<<cB * cS / QPB, TPB, 0, stream>>>(P2, idxMap, TR, AB, AA);
  mlp_kernel<<<2048, 128, 0, stream>>>(TR, P, AB, AA, feat, smp,
                                       w1, b1, g1, be1, w2, b2, g2, be2,
                                       w3, b3, g3, be3, out + cB * cS * 3);
}